// Round 1
// baseline (2790.053 us; speedup 1.0000x reference)
//
#include <hip/hip_runtime.h>
#include <math.h>

#define FHh 480
#define FWw 640
#define NPIX (FHh*FWw)          // 307200
#define NSEMC 16
#define COBS 20
#define MAPC 480
#define VRc 100
#define HZc 80
#define MINZc 13
#define MAXZc 25
#define ZW 12                   // MAXZ-MINZ
#define VOX0_SIZE (VRc*VRc*HZc)            // 800000 (channel 0, full z)
#define VOXS_SIZE (VRc*VRc*NSEMC*ZW)       // 1920000 (ch 1..16, z window only)
#define VOX_TOTAL (VOX0_SIZE + VOXS_SIZE)  // 2720000 floats
#define NB 4

// ---------------- pose + affine params ----------------
__global__ void pose_kernel(const float* __restrict__ pose_obs,
                            const float* __restrict__ poses_last,
                            float* __restrict__ out_p1,
                            float* __restrict__ out_p2,
                            float* __restrict__ params)
{
    int b = threadIdx.x;
    if (b >= NB) return;
    float pl0 = poses_last[b*3+0], pl1 = poses_last[b*3+1], pl2 = poses_last[b*3+2];
    float po0 = pose_obs[b*3+0],  po1 = pose_obs[b*3+1],  po2 = pose_obs[b*3+2];
    const float DEGf = 57.29577951308232f;
    float t0 = pl2 / DEGf;
    float s = sinf(t0), c = cosf(t0);
    float y_new = pl1 + po0*s + po1*c;
    float x_new = pl0 + po0*c - po1*s;
    float t_new = pl2 + po2*DEGf;
    t_new = fmodf(t_new - 180.0f, 360.0f) + 180.0f;
    t_new = fmodf(t_new + 180.0f, 360.0f) - 180.0f;
    out_p1[b*3+0]=x_new; out_p1[b*3+1]=y_new; out_p1[b*3+2]=t_new;
    out_p2[b*3+0]=x_new; out_p2[b*3+1]=y_new; out_p2[b*3+2]=t_new;
    // st_xy = -((p*100/5 - 240)/240), st_t = (90 - t)*pi/180
    float sx = -(((x_new*100.0f)/5.0f - 240.0f)/240.0f);
    float sy = -(((y_new*100.0f)/5.0f - 240.0f)/240.0f);
    float st_t = (90.0f - t_new) * 0.017453292519943295f;
    params[b*4+0] = cosf(st_t);
    params[b*4+1] = sinf(st_t);
    params[b*4+2] = sx;
    params[b*4+3] = sy;
}

// ---------------- trilinear splat into compact voxel grid ----------------
__global__ void splat_kernel(const float* __restrict__ obs,
                             const float* __restrict__ sh,
                             float* __restrict__ vox,
                             int b, float fconst)
{
    int n = blockIdx.x*blockDim.x + threadIdx.x;
    if (n >= NPIX) return;
    int col = n % FWw, row = n / FWw;
    const float* obsb = obs + (size_t)b*COBS*NPIX;
    float depth = obsb[3*NPIX + n];

    const float4 s4 = ((const float4*)sh)[(size_t)b*NPIX + n];
    float sm = (((s4.x + s4.y) + s4.z) + s4.w) / 4.0f;
    float factor = 1.0f + sm;

    float X = ((float)col - 319.5f) * depth / fconst;
    float Z = ((float)(FHh-1-row) - 239.5f) * depth / fconst;
    float x_s = X + 250.0f;
    float z_s = Z + 88.0f;
    float xn = (x_s/5.0f - 50.0f)/100.0f*2.0f;
    float yn = (depth/5.0f - 50.0f)/100.0f*2.0f;
    float zn = (z_s/5.0f - 32.0f)/80.0f*2.0f;
    xn = fminf(fmaxf(xn,-1.0f),1.0f);
    yn = fminf(fmaxf(yn,-1.0f),1.0f);
    zn = fminf(fmaxf(zn,-1.0f),1.0f);
    float pos0 = (xn*100.0f)/2.0f + 50.0f;
    float pos1 = (yn*100.0f)/2.0f + 50.0f;
    float pos2 = (zn*80.0f)/2.0f + 40.0f;
    float f0 = floorf(pos0), f1 = floorf(pos1), f2 = floorf(pos2);

    float sem[NSEMC];
    bool sem_loaded = false;

    #pragma unroll
    for (int cor = 0; cor < 8; ++cor) {
        float q0 = f0 + (float)((cor>>2)&1);
        float q1 = f1 + (float)((cor>>1)&1);
        float q2 = f2 + (float)(cor&1);
        if (!(q0>0.0f && q0<100.0f && q1>0.0f && q1<100.0f && q2>0.0f && q2<80.0f))
            continue;
        float w = (1.0f - fabsf(pos0 - q0));
        w = w * (1.0f - fabsf(pos1 - q1));
        w = w * (1.0f - fabsf(pos2 - q2));
        if (w <= 0.0f) continue;
        int i0=(int)q0, i1=(int)q1, i2=(int)q2;
        int cell = i0*VRc + i1;
        unsafeAtomicAdd(vox + cell*HZc + i2, factor*w);   // channel 0 (feat=1*factor)
        if (i2 >= MINZc && i2 < MAXZc) {
            if (!sem_loaded) {
                #pragma unroll
                for (int c2=0;c2<NSEMC;c2++)
                    sem[c2] = obsb[(4+c2)*NPIX + n] * factor;  // enh = obs*(1+sh_mean)
                sem_loaded = true;
            }
            float* basep = vox + VOX0_SIZE + (size_t)(cell*NSEMC)*ZW + (i2 - MINZc);
            #pragma unroll
            for (int c2=0;c2<NSEMC;c2++)
                unsafeAtomicAdd(basep + c2*ZW, sem[c2]*w);
        }
    }
}

// ---------------- round + z-projection + clip into avwin ----------------
__global__ void proj_kernel(const float* __restrict__ vox,
                            float* __restrict__ avwin,
                            float* __restrict__ fp_out, int b)
{
    int t = blockIdx.x*blockDim.x + threadIdx.x;
    if (t >= VRc*VRc*(NSEMC+1)) return;
    int cell = t % (VRc*VRc);
    int c = t / (VRc*VRc);            // 0..16
    int i = cell / VRc, j = cell % VRc;   // i = p0 (x), j = p1 (y)
    float* avb = avwin + (size_t)b*18*10000;
    if (c == 0) {
        const float* p = vox + (size_t)cell*HZc;
        float all = 0.0f, agent = 0.0f;
        #pragma unroll
        for (int z=0; z<HZc; ++z) {
            float v = rintf(p[z]);        // round half-to-even, like jnp.round
            all += v;
            if (z >= MINZc && z < MAXZc) agent += v;
        }
        float fp = fminf(fmaxf(agent, 0.0f), 1.0f);  // /MAP_T(=1), clip
        float fe = fminf(fmaxf(all,   0.0f), 1.0f);  // /EXP_T(=1), clip
        avb[0*10000 + j*VRc + i] = fp;
        avb[1*10000 + j*VRc + i] = fe;
        fp_out[(size_t)b*10000 + j*VRc + i] = fp;
    } else {
        const float* p = vox + VOX0_SIZE + (size_t)(cell*NSEMC + (c-1))*ZW;
        float agent = 0.0f;
        #pragma unroll
        for (int z=0; z<ZW; ++z) agent += rintf(p[z]);
        avb[(1+c)*10000 + j*VRc + i] = fminf(fmaxf(agent/5.0f, 0.0f), 1.0f);
    }
}

// ---------------- fused double grid_sample + max ----------------
__device__ __forceinline__ float grid1d(int i) {
    return (float)(-1.0 + (double)i * (2.0/479.0));
}

__global__ void map_kernel(const float* __restrict__ maps_last,
                           const float* __restrict__ avwin,
                           const float* __restrict__ params,
                           float* __restrict__ map_out)
{
    int t = blockIdx.x*blockDim.x + threadIdx.x;
    if (t >= NB*MAPC*MAPC) return;
    int w = t % MAPC;
    int h = (t / MAPC) % MAPC;
    int b = t / (MAPC*MAPC);
    float ct = params[b*4+0], st = params[b*4+1];
    float sx = params[b*4+2], sy = params[b*4+3];

    float xg = grid1d(w) + sx;
    float yg = grid1d(h) + sy;
    float xt = ((xg + 1.0f)*479.0f)/2.0f;
    float yt = ((yg + 1.0f)*479.0f)/2.0f;
    float xf = floorf(xt), yf = floorf(yt);

    float acc[18];
    #pragma unroll
    for (int k=0;k<18;k++) acc[k]=0.0f;
    const float* avb = avwin + (size_t)b*18*10000;

    #pragma unroll
    for (int oy=0; oy<2; ++oy) {
        #pragma unroll
        for (int ox=0; ox<2; ++ox) {
            float qx = xf + (float)ox, qy = yf + (float)oy;
            if (!(qx >= 0.0f && qx < 480.0f && qy >= 0.0f && qy < 480.0f)) continue;
            float wo = (ox ? (xt - xf) : (xf + 1.0f - xt))
                     * (oy ? (yt - yf) : (yf + 1.0f - yt));
            int oxi = (int)qx, oyi = (int)qy;
            // rotation sample at pixel (oyi, oxi)
            float gxr = grid1d(oxi), gyr = grid1d(oyi);
            float xr = ct*gxr - st*gyr;
            float yr = st*gxr + ct*gyr;
            float xp = ((xr + 1.0f)*479.0f)/2.0f;
            float yp = ((yr + 1.0f)*479.0f)/2.0f;
            float xpf = floorf(xp), ypf = floorf(yp);
            float R[18];
            #pragma unroll
            for (int k=0;k<18;k++) R[k]=0.0f;
            #pragma unroll
            for (int iy=0; iy<2; ++iy) {
                #pragma unroll
                for (int ix=0; ix<2; ++ix) {
                    float rx = xpf + (float)ix, ry = ypf + (float)iy;
                    if (!(rx >= 0.0f && rx < 480.0f && ry >= 0.0f && ry < 480.0f)) continue;
                    int rxi = (int)rx, ryi = (int)ry;
                    if (ryi < 240 || ryi >= 340 || rxi < 190 || rxi >= 290) continue;  // av==0 outside
                    float wi = (ix ? (xp - xpf) : (xpf + 1.0f - xp))
                             * (iy ? (yp - ypf) : (ypf + 1.0f - yp));
                    const float* p = avb + (ryi-240)*VRc + (rxi-190);
                    #pragma unroll
                    for (int k=0;k<18;k++) R[k] += wi * p[k*10000];
                }
            }
            #pragma unroll
            for (int k=0;k<18;k++) acc[k] += wo * R[k];
        }
    }

    #pragma unroll
    for (int c=0;c<COBS;c++) {
        size_t o = (((size_t)b*COBS + c)*MAPC + h)*MAPC + w;
        float tv = (c==0) ? acc[0] : (c==1) ? acc[1] : (c>=4) ? acc[c-2] : 0.0f;
        map_out[o] = fmaxf(maps_last[o], tv);
    }
}

extern "C" void kernel_launch(void* const* d_in, const int* in_sizes, int n_in,
                              void* d_out, int out_size, void* d_ws, size_t ws_size,
                              hipStream_t stream)
{
    const float* obs        = (const float*)d_in[0];
    const float* pose_obs   = (const float*)d_in[1];
    const float* maps_last  = (const float*)d_in[2];
    const float* poses_last = (const float*)d_in[3];
    const float* sh         = (const float*)d_in[4];
    float* out = (float*)d_out;

    float* fp_out  = out;                       // B*1*100*100 = 40000
    float* map_out = out + 40000;               // B*20*480*480 = 18432000
    float* poses1  = out + 40000 + 18432000;    // 12
    float* poses2  = poses1 + 12;               // 12

    float* params = (float*)d_ws;               // 16 floats
    float* avwin  = params + 16;                // B*18*100*100 = 720000 floats
    // voxel scratch lives in the map_pred output region (10.9MB << 73.7MB),
    // which is only written by map_kernel at the very end (stream-ordered).
    float* vox = map_out;

    // f = FW/2 / tan(radians(FOV/2)), matching python float64 then f32 cast
    double rad = 39.5 * 0.017453292519943295;
    float fconst = (float)(320.0 / tan(rad));

    hipLaunchKernelGGL(pose_kernel, dim3(1), dim3(64), 0, stream,
                       pose_obs, poses_last, poses1, poses2, params);

    for (int b = 0; b < NB; ++b) {
        hipMemsetAsync(vox, 0, (size_t)VOX_TOTAL*sizeof(float), stream);
        hipLaunchKernelGGL(splat_kernel, dim3((NPIX+255)/256), dim3(256), 0, stream,
                           obs, sh, vox, b, fconst);
        hipLaunchKernelGGL(proj_kernel, dim3((VRc*VRc*(NSEMC+1)+255)/256), dim3(256), 0, stream,
                           vox, avwin, fp_out, b);
    }

    hipLaunchKernelGGL(map_kernel, dim3((NB*MAPC*MAPC+255)/256), dim3(256), 0, stream,
                       maps_last, avwin, params, map_out);
}

// Round 2
// 811.997 us; speedup vs baseline: 3.4360x; 3.4360x over previous
//
#include <hip/hip_runtime.h>
#include <math.h>

#define FHh 480
#define FWw 640
#define NPIX (FHh*FWw)          // 307200
#define NSEMC 16
#define COBS 20
#define MAPC 480
#define VRc 100
#define HZc 80
#define MINZc 13
#define MAXZc 25
#define ZW 12
#define NB 4
#define NBINS_DIM 101
#define NBINS_ROW 101           // f1 index range 0..100
#define NBINS_TOTAL (NB*NBINS_DIM*NBINS_ROW)   // 40804
#define COUNTS_PAD 40960        // 1024*40, >= NBINS_TOTAL+1

// ---------------- pose + affine params ----------------
__global__ void pose_kernel(const float* __restrict__ pose_obs,
                            const float* __restrict__ poses_last,
                            float* __restrict__ out_p1,
                            float* __restrict__ out_p2,
                            float* __restrict__ params)
{
    int b = threadIdx.x;
    if (b >= NB) return;
    float pl0 = poses_last[b*3+0], pl1 = poses_last[b*3+1], pl2 = poses_last[b*3+2];
    float po0 = pose_obs[b*3+0],  po1 = pose_obs[b*3+1],  po2 = pose_obs[b*3+2];
    const float DEGf = 57.29577951308232f;
    float t0 = pl2 / DEGf;
    float s = sinf(t0), c = cosf(t0);
    float y_new = pl1 + po0*s + po1*c;
    float x_new = pl0 + po0*c - po1*s;
    float t_new = pl2 + po2*DEGf;
    t_new = fmodf(t_new - 180.0f, 360.0f) + 180.0f;
    t_new = fmodf(t_new + 180.0f, 360.0f) - 180.0f;
    out_p1[b*3+0]=x_new; out_p1[b*3+1]=y_new; out_p1[b*3+2]=t_new;
    out_p2[b*3+0]=x_new; out_p2[b*3+1]=y_new; out_p2[b*3+2]=t_new;
    float sx = -(((x_new*100.0f)/5.0f - 240.0f)/240.0f);
    float sy = -(((y_new*100.0f)/5.0f - 240.0f)/240.0f);
    float st_t = (90.0f - t_new) * 0.017453292519943295f;
    params[b*4+0] = cosf(st_t);
    params[b*4+1] = sinf(st_t);
    params[b*4+2] = sx;
    params[b*4+3] = sy;
}

// ---------------- per-pixel projection math (shared by pass A) ----------------
__device__ __forceinline__ float4 pixel_pos(const float* __restrict__ obsb,
                                            const float* __restrict__ sh,
                                            int b, int n, float fconst)
{
    int col = n % FWw, row = n / FWw;
    float depth = obsb[3*NPIX + n];
    const float4 s4 = ((const float4*)sh)[(size_t)b*NPIX + n];
    float sm = (((s4.x + s4.y) + s4.z) + s4.w) / 4.0f;
    float factor = 1.0f + sm;

    float X = ((float)col - 319.5f) * depth / fconst;
    float Z = ((float)(FHh-1-row) - 239.5f) * depth / fconst;
    float x_s = X + 250.0f;
    float z_s = Z + 88.0f;
    float xn = (x_s/5.0f - 50.0f)/100.0f*2.0f;
    float yn = (depth/5.0f - 50.0f)/100.0f*2.0f;
    float zn = (z_s/5.0f - 32.0f)/80.0f*2.0f;
    xn = fminf(fmaxf(xn,-1.0f),1.0f);
    yn = fminf(fmaxf(yn,-1.0f),1.0f);
    zn = fminf(fmaxf(zn,-1.0f),1.0f);
    float pos0 = (xn*100.0f)/2.0f + 50.0f;
    float pos1 = (yn*100.0f)/2.0f + 50.0f;
    float pos2 = (zn*80.0f)/2.0f + 40.0f;
    return make_float4(pos0, pos1, pos2, factor);
}

// ---------------- pass A: bin counting ----------------
__global__ void bin_count_kernel(const float* __restrict__ obs,
                                 const float* __restrict__ sh,
                                 float4* __restrict__ tmpPos,
                                 int* __restrict__ auxBid,
                                 int* __restrict__ auxRank,
                                 int* __restrict__ counts,
                                 float fconst)
{
    int g = blockIdx.x*blockDim.x + threadIdx.x;
    if (g >= NB*NPIX) return;
    int b = g / NPIX, n = g % NPIX;
    const float* obsb = obs + (size_t)b*COBS*NPIX;
    float4 P = pixel_pos(obsb, sh, b, n, fconst);
    int f0 = (int)floorf(P.x); if (f0 > 100) f0 = 100;
    int f1 = (int)floorf(P.y); if (f1 > 100) f1 = 100;
    int bid = (b*NBINS_DIM + f0)*NBINS_ROW + f1;
    int r = atomicAdd(&counts[bid], 1);
    tmpPos[g] = P;
    auxBid[g] = bid;
    auxRank[g] = r;
}

// ---------------- exclusive scan over padded counts (single block) ----------------
__global__ void scan_kernel(int* __restrict__ counts)
{
    __shared__ int part[1024];
    int t = threadIdx.x;
    const int CHUNK = COUNTS_PAD / 1024;   // 40
    int base = t*CHUNK;
    int s = 0;
    for (int k = 0; k < CHUNK; ++k) s += counts[base+k];
    part[t] = s;
    __syncthreads();
    for (int off = 1; off < 1024; off <<= 1) {
        int v = (t >= off) ? part[t-off] : 0;
        __syncthreads();
        part[t] += v;
        __syncthreads();
    }
    int run = part[t] - s;   // exclusive base for this chunk
    for (int k = 0; k < CHUNK; ++k) {
        int c = counts[base+k];
        counts[base+k] = run;
        run += c;
    }
}

// ---------------- pass C: scatter payload into binned order ----------------
__global__ void scatter_kernel(const float4* __restrict__ tmpPos,
                               const int* __restrict__ auxBid,
                               const int* __restrict__ auxRank,
                               const int* __restrict__ offsets,
                               float4* __restrict__ payloadPos,
                               int* __restrict__ payloadN)
{
    int g = blockIdx.x*blockDim.x + threadIdx.x;
    if (g >= NB*NPIX) return;
    int dst = offsets[auxBid[g]] + auxRank[g];
    payloadPos[dst] = tmpPos[g];
    payloadN[dst] = g % NPIX;
}

// ---------------- pass B: gather into LDS, round, project, clip ----------------
__global__ __launch_bounds__(128)
void gather_kernel(const float* __restrict__ obs,
                   const float4* __restrict__ payloadPos,
                   const int* __restrict__ payloadN,
                   const int* __restrict__ offsets,
                   float* __restrict__ avwin,
                   float* __restrict__ fp_out)
{
    int cell = blockIdx.x;          // j*100 + i
    int b = blockIdx.y;
    int tid = threadIdx.x;
    int i = cell % VRc, j = cell / VRc;

    __shared__ float acc[HZc + NSEMC*ZW];   // 80 + 192 = 272
    for (int k = tid; k < HZc + NSEMC*ZW; k += 128) acc[k] = 0.0f;
    __syncthreads();

    if (i > 0 && j > 0) {
        const float* obsb = obs + (size_t)b*COBS*NPIX;
        #pragma unroll
        for (int fi = 0; fi < 2; ++fi) {
            int f0r = i - 1 + fi;
            int rb = (b*NBINS_DIM + f0r)*NBINS_ROW;
            int s = offsets[rb + j - 1];
            int e = offsets[rb + j + 1];
            for (int idx = s + tid; idx < e; idx += 128) {
                float4 P = payloadPos[idx];
                float wx = 1.0f - fabsf(P.x - (float)i);
                float wy = 1.0f - fabsf(P.y - (float)j);
                float wxy = wx * wy;
                if (wxy <= 0.0f) continue;
                float f2 = floorf(P.z);
                float wsem0 = 0.0f, wsem1 = 0.0f;
                int qA = (int)f2, qB = qA + 1;
                if (qA > 0 && qA < HZc) {
                    float w = wxy * (1.0f - fabsf(P.z - (float)qA));
                    if (w > 0.0f) {
                        atomicAdd(&acc[qA], P.w * w);
                        if (qA >= MINZc && qA < MAXZc) wsem0 = w;
                    }
                }
                if (qB > 0 && qB < HZc) {
                    float w = wxy * (1.0f - fabsf(P.z - (float)qB));
                    if (w > 0.0f) {
                        atomicAdd(&acc[qB], P.w * w);
                        if (qB >= MINZc && qB < MAXZc) wsem1 = w;
                    }
                }
                if (wsem0 > 0.0f || wsem1 > 0.0f) {
                    int n = payloadN[idx];
                    int zA = qA - MINZc, zB = qB - MINZc;
                    #pragma unroll
                    for (int c = 0; c < NSEMC; ++c) {
                        float enh = obsb[(4+c)*NPIX + n] * P.w;
                        if (wsem0 > 0.0f) atomicAdd(&acc[HZc + c*ZW + zA], enh * wsem0);
                        if (wsem1 > 0.0f) atomicAdd(&acc[HZc + c*ZW + zB], enh * wsem1);
                    }
                }
            }
        }
    }
    __syncthreads();

    float* avb = avwin + (size_t)b*18*10000;
    if (tid < NSEMC) {
        float sum = 0.0f;
        #pragma unroll
        for (int z = 0; z < ZW; ++z) sum += rintf(acc[HZc + tid*ZW + z]);
        avb[(2+tid)*10000 + cell] = fminf(fmaxf(sum/5.0f, 0.0f), 1.0f);
    } else if (tid == 16) {
        float agent = 0.0f;
        #pragma unroll
        for (int z = MINZc; z < MAXZc; ++z) agent += rintf(acc[z]);
        float v = fminf(fmaxf(agent, 0.0f), 1.0f);
        avb[0*10000 + cell] = v;
        fp_out[(size_t)b*10000 + cell] = v;
    } else if (tid == 17) {
        float all = 0.0f;
        for (int z = 0; z < HZc; ++z) all += rintf(acc[z]);
        avb[1*10000 + cell] = fminf(fmaxf(all, 0.0f), 1.0f);
    }
}

// ---------------- fused double grid_sample + max ----------------
__device__ __forceinline__ float grid1d(int i) {
    return (float)(-1.0 + (double)i * (2.0/479.0));
}

__global__ void map_kernel(const float* __restrict__ maps_last,
                           const float* __restrict__ avwin,
                           const float* __restrict__ params,
                           float* __restrict__ map_out)
{
    int t = blockIdx.x*blockDim.x + threadIdx.x;
    if (t >= NB*MAPC*MAPC) return;
    int w = t % MAPC;
    int h = (t / MAPC) % MAPC;
    int b = t / (MAPC*MAPC);
    float ct = params[b*4+0], st = params[b*4+1];
    float sx = params[b*4+2], sy = params[b*4+3];

    float xg = grid1d(w) + sx;
    float yg = grid1d(h) + sy;
    float xt = ((xg + 1.0f)*479.0f)/2.0f;
    float yt = ((yg + 1.0f)*479.0f)/2.0f;
    float xf = floorf(xt), yf = floorf(yt);

    float acc[18];
    #pragma unroll
    for (int k=0;k<18;k++) acc[k]=0.0f;
    const float* avb = avwin + (size_t)b*18*10000;

    #pragma unroll
    for (int oy=0; oy<2; ++oy) {
        #pragma unroll
        for (int ox=0; ox<2; ++ox) {
            float qx = xf + (float)ox, qy = yf + (float)oy;
            if (!(qx >= 0.0f && qx < 480.0f && qy >= 0.0f && qy < 480.0f)) continue;
            float wo = (ox ? (xt - xf) : (xf + 1.0f - xt))
                     * (oy ? (yt - yf) : (yf + 1.0f - yt));
            int oxi = (int)qx, oyi = (int)qy;
            float gxr = grid1d(oxi), gyr = grid1d(oyi);
            float xr = ct*gxr - st*gyr;
            float yr = st*gxr + ct*gyr;
            float xp = ((xr + 1.0f)*479.0f)/2.0f;
            float yp = ((yr + 1.0f)*479.0f)/2.0f;
            float xpf = floorf(xp), ypf = floorf(yp);
            float R[18];
            #pragma unroll
            for (int k=0;k<18;k++) R[k]=0.0f;
            #pragma unroll
            for (int iy=0; iy<2; ++iy) {
                #pragma unroll
                for (int ix=0; ix<2; ++ix) {
                    float rx = xpf + (float)ix, ry = ypf + (float)iy;
                    if (!(rx >= 0.0f && rx < 480.0f && ry >= 0.0f && ry < 480.0f)) continue;
                    int rxi = (int)rx, ryi = (int)ry;
                    if (ryi < 240 || ryi >= 340 || rxi < 190 || rxi >= 290) continue;
                    float wi = (ix ? (xp - xpf) : (xpf + 1.0f - xp))
                             * (iy ? (yp - ypf) : (yp + 1.0f - yp - (yp - ypf)));
                    // simplify: weight in y
                    wi = (ix ? (xp - xpf) : (xpf + 1.0f - xp))
                       * (iy ? (yp - ypf) : (ypf + 1.0f - yp));
                    const float* p = avb + (ryi-240)*VRc + (rxi-190);
                    #pragma unroll
                    for (int k=0;k<18;k++) R[k] += wi * p[k*10000];
                }
            }
            #pragma unroll
            for (int k=0;k<18;k++) acc[k] += wo * R[k];
        }
    }

    #pragma unroll
    for (int c=0;c<COBS;c++) {
        size_t o = (((size_t)b*COBS + c)*MAPC + h)*MAPC + w;
        float tv = (c==0) ? acc[0] : (c==1) ? acc[1] : (c>=4) ? acc[c-2] : 0.0f;
        map_out[o] = fmaxf(maps_last[o], tv);
    }
}

extern "C" void kernel_launch(void* const* d_in, const int* in_sizes, int n_in,
                              void* d_out, int out_size, void* d_ws, size_t ws_size,
                              hipStream_t stream)
{
    const float* obs        = (const float*)d_in[0];
    const float* pose_obs   = (const float*)d_in[1];
    const float* maps_last  = (const float*)d_in[2];
    const float* poses_last = (const float*)d_in[3];
    const float* sh         = (const float*)d_in[4];
    float* out = (float*)d_out;

    float* fp_out  = out;                       // B*1*100*100 = 40000
    float* map_out = out + 40000;               // B*20*480*480 = 18432000
    float* poses1  = out + 40000 + 18432000;    // 12
    float* poses2  = poses1 + 12;               // 12

    // d_ws: params + avwin only (proven size from round 1)
    float* params = (float*)d_ws;               // 16 floats
    float* avwin  = params + 16;                // B*18*100*100 = 720000 floats

    // Scratch placed inside the map_pred output region (written only by the
    // final map_kernel; everything here is consumed before that launch).
    const int NTOT = NB*NPIX;                   // 1,228,800
    float4* tmpPos     = (float4*)map_out;                       // 4,915,200 floats
    float4* payloadPos = (float4*)(map_out + 4915200);           // 4,915,200 floats
    int*    auxBid     = (int*)(map_out + 9830400);              // 1,228,800
    int*    auxRank    = (int*)(map_out + 11059200);             // 1,228,800
    int*    payloadN   = (int*)(map_out + 12288000);             // 1,228,800
    int*    counts     = (int*)(map_out + 13516800);             // 40,960 ints
    // total: 13,557,760 floats < 18,432,000 available

    double rad = 39.5 * 0.017453292519943295;
    float fconst = (float)(320.0 / tan(rad));

    hipLaunchKernelGGL(pose_kernel, dim3(1), dim3(64), 0, stream,
                       pose_obs, poses_last, poses1, poses2, params);

    hipMemsetAsync(counts, 0, (size_t)COUNTS_PAD*sizeof(int), stream);

    hipLaunchKernelGGL(bin_count_kernel, dim3((NTOT+255)/256), dim3(256), 0, stream,
                       obs, sh, tmpPos, auxBid, auxRank, counts, fconst);

    hipLaunchKernelGGL(scan_kernel, dim3(1), dim3(1024), 0, stream, counts);

    hipLaunchKernelGGL(scatter_kernel, dim3((NTOT+255)/256), dim3(256), 0, stream,
                       tmpPos, auxBid, auxRank, counts, payloadPos, payloadN);

    hipLaunchKernelGGL(gather_kernel, dim3(10000, NB), dim3(128), 0, stream,
                       obs, payloadPos, payloadN, counts, avwin, fp_out);

    hipLaunchKernelGGL(map_kernel, dim3((NB*MAPC*MAPC+255)/256), dim3(256), 0, stream,
                       maps_last, avwin, params, map_out);
}